// Round 5
// baseline (1260.018 us; speedup 1.0000x reference)
//
#include <hip/hip_runtime.h>
#include <hip/hip_bf16.h>
#include <stdint.h>

#define NROWS 8192
#define DDIM  1024
#define NQ    30
#define MARGINF 2.0f

typedef __attribute__((ext_vector_type(8))) short bf16x8;   // 8 bf16 (4 VGPRs)
typedef __attribute__((ext_vector_type(4))) float f32x4;    // MFMA accum
typedef __attribute__((ext_vector_type(4))) int   i32x4;
typedef __attribute__((ext_vector_type(8))) int   i32x8;

static __device__ __forceinline__ unsigned short f2bf(float f) {
  union { float f; unsigned u; } c; c.f = f;
  return (unsigned short)((c.u + 0x7fffu + ((c.u >> 16) & 1u)) >> 16);  // RNE
}

// fp32 -> OCP e4m3fn (RNE, saturate to 448, subnormals handled)
static __device__ __forceinline__ unsigned char f2fp8(float x) {
  union { float f; unsigned u; } c; c.f = x;
  const unsigned sign = (c.u >> 24) & 0x80u;
  const unsigned au = c.u & 0x7FFFFFFFu;
  if (au >= 0x43E00000u) return (unsigned char)(sign | 0x7Eu);   // clamp +-448
  if (au < 0x3C800000u) {                                        // |x| < 2^-6
    int mi = (int)(fabsf(c.f) * 512.0f + 0.5f);                  // subnormal step 2^-9
    if (mi > 7) return (unsigned char)(sign | 0x08u);
    return (unsigned char)(sign | (unsigned)mi);
  }
  unsigned u = au + 0x7FFFFu + ((au >> 20) & 1u);                // RNE at bit 20
  int e = (int)(u >> 23) - 127 + 7;
  unsigned m = (u >> 20) & 7u;
  if (e >= 16) return (unsigned char)(sign | 0x7Eu);
  return (unsigned char)(sign | ((unsigned)e << 4) | m);
}

static __device__ __forceinline__ void gload_lds16(const void* g, void* l) {
  __builtin_amdgcn_global_load_lds(
      (const __attribute__((address_space(1))) void*)g,
      (__attribute__((address_space(3))) void*)l, 16, 0, 0);
}

// ---------------- prep: bf16 + fp8 cast, row norms, pos term, rowMin init ---
__global__ __launch_bounds__(256) void prep_kernel(
    const float* __restrict__ o1, const float* __restrict__ o2,
    unsigned short* __restrict__ o1b, unsigned short* __restrict__ o2b,
    unsigned char* __restrict__ o1q, unsigned char* __restrict__ o2q,
    float* __restrict__ a2, float* __restrict__ b2, float* __restrict__ posr,
    unsigned int* __restrict__ rowMin, int* __restrict__ flag)
{
  const int row = blockIdx.x;
  const int t = threadIdx.x;
  const float4* p1 = (const float4*)(o1 + (size_t)row * DDIM);
  const float4* p2 = (const float4*)(o2 + (size_t)row * DDIM);
  float4 x1 = p1[t];
  float4 x2 = p2[t];
  float s1, s2, sp;
  {
    float a0 = x1.x, a1 = x1.y, aa2 = x1.z, a3 = x1.w;
    float b0 = x2.x, b1 = x2.y, bb2 = x2.z, b3 = x2.w;
    s1 = a0*a0 + a1*a1 + aa2*aa2 + a3*a3;
    s2 = b0*b0 + b1*b1 + bb2*bb2 + b3*b3;
    float d0 = b0-a0, d1 = b1-a1, d2 = bb2-aa2, d3 = b3-a3;
    sp = d0*d0 + d1*d1 + d2*d2 + d3*d3;
    *(ushort4*)(o1b + (size_t)row * DDIM + t * 4) =
        make_ushort4(f2bf(a0), f2bf(a1), f2bf(aa2), f2bf(a3));
    *(ushort4*)(o2b + (size_t)row * DDIM + t * 4) =
        make_ushort4(f2bf(b0), f2bf(b1), f2bf(bb2), f2bf(b3));
    *(uchar4*)(o1q + (size_t)row * DDIM + t * 4) =
        make_uchar4(f2fp8(a0), f2fp8(a1), f2fp8(aa2), f2fp8(a3));
    *(uchar4*)(o2q + (size_t)row * DDIM + t * 4) =
        make_uchar4(f2fp8(b0), f2fp8(b1), f2fp8(bb2), f2fp8(b3));
  }
  for (int s = 1; s < 64; s <<= 1) {
    s1 += __shfl_xor(s1, s);
    s2 += __shfl_xor(s2, s);
    sp += __shfl_xor(sp, s);
  }
  __shared__ float r1[4], r2[4], rp[4];
  const int wv = t >> 6;
  if ((t & 63) == 0) { r1[wv] = s1; r2[wv] = s2; rp[wv] = sp; }
  __syncthreads();
  if (t == 0) {
    a2[row]   = r1[0] + r1[1] + r1[2] + r1[3];
    b2[row]   = r2[0] + r2[1] + r2[2] + r2[3];
    posr[row] = rp[0] + rp[1] + rp[2] + rp[3];
    rowMin[row] = 0x7F800000u;           // +inf bits
    if (row == 0) *flag = 0;
  }
}

// ============================================================================
// MX-FP8 GEMM -> rowMin. 128x128 tile, BK=128, 4 waves (2x2), m97-style
// 2-barrier loop, mfma_scale_f32_16x16x128_f8f6f4 with unit scales (0x7F).
// LDS 32 KB single-buffered. Swizzle: 8x16B slots/row, slot ^= row&7,
// both-sides (pre-swizzled global source, swizzled ds_read). Per quarter-wave
// reads: 2 lanes/slot -> conflict-free (m136: 2-way free).
// ============================================================================
__global__ __launch_bounds__(256) void gemm8_kernel(
    const unsigned char* __restrict__ A, const unsigned char* __restrict__ B,
    const float* __restrict__ a2, const float* __restrict__ b2,
    unsigned int* __restrict__ rowMin)
{
  __shared__ __align__(16) unsigned char lA[128 * 128];   // 16 KB
  __shared__ __align__(16) unsigned char lB[128 * 128];   // 16 KB
  const int tid  = threadIdx.x;
  const int lane = tid & 63;
  const int wave = tid >> 6;
  const int bm = blockIdx.y * 128;
  const int bn = blockIdx.x * 128;
  const int wm = (wave >> 1) * 64;
  const int wn = (wave & 1) * 64;

  // staging: 4 chunks x 32 rows per matrix; thread -> (row=q*32+(tid>>3),
  // 16B slot (tid&7)); source slot pre-swizzled, LDS dest linear.
  const int srow = tid >> 3;                       // 0..31
  const int slot = (tid & 7) ^ (srow & 7);
  const unsigned char* Ast = A + (size_t)(bm + srow) * DDIM + slot * 16;
  const unsigned char* Bst = B + (size_t)(bn + srow) * DDIM + slot * 16;

  // read side: frag = 32B of row r at k-quarter c32; physical slots
  // (2*c32)^(r&7) and that ^1.
  const int rlane = lane & 15;
  const int c32   = lane >> 4;
  const int s0    = ((2 * c32) ^ (rlane & 7)) * 16;   // byte offset of lo slot
  const int s1    = s0 ^ 16;                          // hi slot

  f32x4 acc[4][4];
#pragma unroll
  for (int mi = 0; mi < 4; ++mi)
#pragma unroll
    for (int ni = 0; ni < 4; ++ni)
      acc[mi][ni] = (f32x4)0.0f;

  for (int kt = 0; kt < 8; ++kt) {
    const int kb = kt * 128;
#pragma unroll
    for (int q = 0; q < 4; ++q) {
      gload_lds16(Ast + (size_t)q * 32 * DDIM + kb, lA + q * 4096 + tid * 16);
      gload_lds16(Bst + (size_t)q * 32 * DDIM + kb, lB + q * 4096 + tid * 16);
    }
    __syncthreads();

    i32x8 af[4], bfr[4];
#pragma unroll
    for (int mi = 0; mi < 4; ++mi) {
      const unsigned char* p = lA + (wm + mi * 16 + rlane) * 128;
      i32x4 lo = *(const i32x4*)(p + s0);
      i32x4 hi = *(const i32x4*)(p + s1);
      af[mi] = __builtin_shufflevector(lo, hi, 0, 1, 2, 3, 4, 5, 6, 7);
    }
#pragma unroll
    for (int ni = 0; ni < 4; ++ni) {
      const unsigned char* p = lB + (wn + ni * 16 + rlane) * 128;
      i32x4 lo = *(const i32x4*)(p + s0);
      i32x4 hi = *(const i32x4*)(p + s1);
      bfr[ni] = __builtin_shufflevector(lo, hi, 0, 1, 2, 3, 4, 5, 6, 7);
    }
#pragma unroll
    for (int mi = 0; mi < 4; ++mi)
#pragma unroll
      for (int ni = 0; ni < 4; ++ni)
        acc[mi][ni] = __builtin_amdgcn_mfma_scale_f32_16x16x128_f8f6f4(
            af[mi], bfr[ni], acc[mi][ni], 0 /*fp8*/, 0 /*fp8*/,
            0, 0x7F7F7F7F, 0, 0x7F7F7F7F);   // unit e8m0 scales
    __syncthreads();
  }

  // epilogue: per-row min of sq -> atomicMin. C/D: col=lane&15, row=(lane>>4)*4+j
#pragma unroll
  for (int mi = 0; mi < 4; ++mi) {
#pragma unroll
    for (int j = 0; j < 4; ++j) {
      const int i = bm + wm + mi * 16 + ((lane >> 4) << 2) + j;
      const float av = a2[i];
      float mn = __builtin_inff();
#pragma unroll
      for (int ni = 0; ni < 4; ++ni) {
        const int jj = bn + wn + ni * 16 + rlane;
        mn = fminf(mn, av + b2[jj] - 2.0f * acc[mi][ni][j]);
      }
#pragma unroll
      for (int s = 1; s < 16; s <<= 1) mn = fminf(mn, __shfl_xor(mn, s));
      if (rlane == 0) atomicMin(&rowMin[i], __float_as_uint(fmaxf(mn, 0.0f)));
    }
  }
}

// ---------------- 128^2 bf16 GEMM (flag-gated exact-path sq store) ----------
template<int STORE_SQ>
__global__ __launch_bounds__(256) void gemm_kernel(
    const unsigned short* __restrict__ A, const unsigned short* __restrict__ B,
    const float* __restrict__ a2, const float* __restrict__ b2,
    unsigned int* __restrict__ rowMin, const int* __restrict__ flag,
    float* __restrict__ sqbuf, int jBase, int chunkCols)
{
  if (STORE_SQ) { if (*flag == 0) return; }   // never taken on benign data
  __shared__ __align__(16) unsigned short lA[128 * 32];
  __shared__ __align__(16) unsigned short lB[128 * 32];
  const int tid  = threadIdx.x;
  const int lane = tid & 63;
  const int wave = tid >> 6;
  const int bm = blockIdx.y * 128;
  const int bn = blockIdx.x * 128;
  const int wm = (wave >> 1) * 64;
  const int wn = (wave & 1) * 64;

  f32x4 acc[4][4];
#pragma unroll
  for (int mi = 0; mi < 4; ++mi)
#pragma unroll
    for (int ni = 0; ni < 4; ++ni)
      acc[mi][ni] = (f32x4)0.0f;

  const unsigned short* Ab = A + (size_t)bm * DDIM;
  const unsigned short* Bb = B + (size_t)(jBase + bn) * DDIM;
  const int stRow  = lane >> 2;
  const int stColH = (lane & 3) * 8;

  for (int kt = 0; kt < DDIM / 32; ++kt) {
#pragma unroll
    for (int p = 0; p < 2; ++p) {
      const int off = (p * 4 + wave) * 1024;
      const int r0  = off >> 6;
      gload_lds16(Ab + (size_t)(r0 + stRow) * DDIM + kt * 32 + stColH, (char*)lA + off);
      gload_lds16(Bb + (size_t)(r0 + stRow) * DDIM + kt * 32 + stColH, (char*)lB + off);
    }
    __syncthreads();

    bf16x8 af[4], bfr[4];
#pragma unroll
    for (int mi = 0; mi < 4; ++mi) {
      const int r = wm + mi * 16 + (lane & 15);
      af[mi] = *(const bf16x8*)((const char*)lA + r * 64 + (lane >> 4) * 16);
    }
#pragma unroll
    for (int ni = 0; ni < 4; ++ni) {
      const int r = wn + ni * 16 + (lane & 15);
      bfr[ni] = *(const bf16x8*)((const char*)lB + r * 64 + (lane >> 4) * 16);
    }
#pragma unroll
    for (int mi = 0; mi < 4; ++mi)
#pragma unroll
      for (int ni = 0; ni < 4; ++ni)
        acc[mi][ni] = __builtin_amdgcn_mfma_f32_16x16x32_bf16(af[mi], bfr[ni], acc[mi][ni], 0, 0, 0);
    __syncthreads();
  }

  if (STORE_SQ == 0) {
#pragma unroll
    for (int mi = 0; mi < 4; ++mi) {
#pragma unroll
      for (int j = 0; j < 4; ++j) {
        const int i = bm + wm + mi * 16 + ((lane >> 4) << 2) + j;
        const float av = a2[i];
        float mn = __builtin_inff();
#pragma unroll
        for (int ni = 0; ni < 4; ++ni) {
          const int jj = bn + wn + ni * 16 + (lane & 15);
          mn = fminf(mn, av + b2[jj] - 2.0f * acc[mi][ni][j]);
        }
#pragma unroll
        for (int s = 1; s < 16; s <<= 1) mn = fminf(mn, __shfl_xor(mn, s));
        if ((lane & 15) == 0) atomicMin(&rowMin[i], __float_as_uint(fmaxf(mn, 0.0f)));
      }
    }
  } else {
#pragma unroll
    for (int mi = 0; mi < 4; ++mi) {
#pragma unroll
      for (int j = 0; j < 4; ++j) {
        const int i = bm + wm + mi * 16 + ((lane >> 4) << 2) + j;
        const float av = a2[i];
#pragma unroll
        for (int ni = 0; ni < 4; ++ni) {
          const int jj = bn + wn + ni * 16 + (lane & 15);
          sqbuf[(size_t)i * chunkCols + jj] = av + b2[jBase + jj] - 2.0f * acc[mi][ni][j];
        }
      }
    }
  }
}

// ---------------- flag: any row with clamped min-sq < 256 (dist < 16)? -----
// Threshold is (MARGIN+slack)^2 inflated far above fp8 dot-error (sigma~4 on
// sq~2048) while any genuine dist<2 pair lands orders below it.
__global__ __launch_bounds__(256) void flag_kernel(const unsigned int* __restrict__ rowMin,
                                                   int* __restrict__ flag)
{
  const int i = blockIdx.x * 256 + threadIdx.x;
  if (i < NROWS && rowMin[i] < 0x43800000u /* bits(256.0f) */) atomicExch(flag, 1);
}

// ---------------- exact top-30 per row (fallback; flag-gated) ---------------
template<int VPL>
__global__ __launch_bounds__(64) void select_kernel(
    const float* __restrict__ sqbuf, const int* __restrict__ flag,
    float* __restrict__ tv, int* __restrict__ ti, int jBase, int isFirst)
{
  if (*flag == 0) return;
  const int row = blockIdx.x, lane = threadIdx.x;
  const int CH = VPL * 64;
  float v[VPL];
#pragma unroll
  for (int q = 0; q < VPL; ++q)
    v[q] = sqbuf[(size_t)row * CH + q * 64 + lane];
  float cv; int ci;
  if (isFirst) { cv = __builtin_inff(); ci = 0x7fffffff; }
  else {
    cv = (lane < NQ) ? tv[row * 32 + lane] : __builtin_inff();
    ci = (lane < NQ) ? ti[row * 32 + lane] : 0x7fffffff;
  }
  for (int k = 0; k < NQ; ++k) {
    float mv = cv; int mi_ = ci;
#pragma unroll
    for (int q = 0; q < VPL; ++q) {
      const int col = jBase + q * 64 + lane;
      const bool b = (v[q] < mv) || (v[q] == mv && col < mi_);
      mv  = b ? v[q] : mv;
      mi_ = b ? col  : mi_;
    }
#pragma unroll
    for (int s = 1; s < 64; s <<= 1) {
      const float ov = __shfl_xor(mv, s);
      const int   oi = __shfl_xor(mi_, s);
      const bool b = (ov < mv) || (ov == mv && oi < mi_);
      mv  = b ? ov : mv;
      mi_ = b ? oi : mi_;
    }
    if (mi_ == ci) cv = __builtin_inff();
    else if (mi_ >= jBase) {
      const int rel = mi_ - jBase;
      if ((rel & 63) == lane) {
        const int lq = rel >> 6;
#pragma unroll
        for (int q = 0; q < VPL; ++q) if (q == lq) v[q] = __builtin_inff();
      }
    }
    if (lane == 0) { tv[row * 32 + k] = mv; ti[row * 32 + k] = mi_; }
  }
}

// ---------------- final reduction ------------------------------------------
__global__ __launch_bounds__(256) void final_kernel(
    const float* __restrict__ posr, const float* __restrict__ tv,
    const int* __restrict__ ti, const int* __restrict__ rn,
    const int* __restrict__ flag, float* __restrict__ out)
{
  const int t = threadIdx.x;
  const int useNeg = (*flag != 0);
  double ps = 0.0, ns = 0.0;
  for (int r = t; r < NROWS; r += 256) {
    ps += (double)posr[r];
    if (useNeg) {
      int k = rn[r];
      const int sel = ti[r * 32 + k];
      if (sel == r) k = (k + 1) % NQ;
      const float d = sqrtf(fmaxf(tv[r * 32 + k], 0.0f));
      ns += (double)fmaxf(MARGINF - d, 0.0f);
    }
  }
  __shared__ double sp[256], sn[256];
  sp[t] = ps; sn[t] = ns;
  __syncthreads();
  for (int s = 128; s > 0; s >>= 1) {
    if (t < s) { sp[t] += sp[t + s]; sn[t] += sn[t + s]; }
    __syncthreads();
  }
  if (t == 0) out[0] = (float)(sp[0] / NROWS + sn[0] / NROWS);
}

extern "C" void kernel_launch(void* const* d_in, const int* in_sizes, int n_in,
                              void* d_out, int out_size, void* d_ws, size_t ws_size,
                              hipStream_t stream) {
  (void)in_sizes; (void)n_in; (void)out_size;
  const float* o1 = (const float*)d_in[0];
  const float* o2 = (const float*)d_in[1];
  const int*   rn = (const int*)d_in[2];
  float* out = (float*)d_out;

  char* ws = (char*)d_ws;
  size_t off = 0;
  auto alloc = [&](size_t b) { void* p = ws + off; off += (b + 255) & ~(size_t)255; return p; };
  unsigned short* o1b = (unsigned short*)alloc((size_t)NROWS * DDIM * 2);  // 16 MB
  unsigned short* o2b = (unsigned short*)alloc((size_t)NROWS * DDIM * 2);  // 16 MB
  unsigned char*  o1q = (unsigned char*)alloc((size_t)NROWS * DDIM);      //  8 MB
  unsigned char*  o2q = (unsigned char*)alloc((size_t)NROWS * DDIM);      //  8 MB
  float* a2   = (float*)alloc((size_t)NROWS * 4);
  float* b2   = (float*)alloc((size_t)NROWS * 4);
  float* posr = (float*)alloc((size_t)NROWS * 4);
  unsigned int* rowMin = (unsigned int*)alloc((size_t)NROWS * 4);
  int*   flag = (int*)alloc(256);
  float* tv   = (float*)alloc((size_t)NROWS * 32 * 4);
  int*   ti   = (int*)alloc((size_t)NROWS * 32 * 4);
  const size_t remain = ws_size > off ? ws_size - off : 0;
  int chunk;
  if      (remain >= (size_t)NROWS * 8192 * 4) chunk = 8192;
  else if (remain >= (size_t)NROWS * 2048 * 4) chunk = 2048;
  else if (remain >= (size_t)NROWS * 512 * 4)  chunk = 512;
  else                                         chunk = 128;
  float* sqbuf = (float*)(ws + off);

  prep_kernel<<<NROWS, 256, 0, stream>>>(o1, o2, o1b, o2b, o1q, o2q,
                                         a2, b2, posr, rowMin, flag);
  gemm8_kernel<<<dim3(64, 64), 256, 0, stream>>>(o1q, o2q, a2, b2, rowMin);
  flag_kernel<<<dim3(NROWS / 256), 256, 0, stream>>>(rowMin, flag);
  const int nch = NROWS / chunk;
  for (int c = 0; c < nch; ++c) {
    gemm_kernel<1><<<dim3(chunk / 128, 64), 256, 0, stream>>>(o1b, o2b, a2, b2, rowMin, flag,
                                                              sqbuf, c * chunk, chunk);
    const int first = (c == 0);
    if      (chunk == 8192) select_kernel<128><<<NROWS, 64, 0, stream>>>(sqbuf, flag, tv, ti, c * chunk, first);
    else if (chunk == 2048) select_kernel<32><<<NROWS, 64, 0, stream>>>(sqbuf, flag, tv, ti, c * chunk, first);
    else if (chunk == 512)  select_kernel<8><<<NROWS, 64, 0, stream>>>(sqbuf, flag, tv, ti, c * chunk, first);
    else                    select_kernel<2><<<NROWS, 64, 0, stream>>>(sqbuf, flag, tv, ti, c * chunk, first);
  }
  final_kernel<<<1, 256, 0, stream>>>(posr, tv, ti, rn, flag, out);
}

// Round 6
// 139.553 us; speedup vs baseline: 9.0289x; 9.0289x over previous
//
#include <hip/hip_runtime.h>
#include <hip/hip_bf16.h>
#include <stdint.h>

#define NROWS 8192
#define DDIM  1024
#define NQ    30
#define MARGINF 2.0f
#define NPROJ 64

typedef __attribute__((ext_vector_type(8))) short bf16x8;   // 8 bf16 (4 VGPRs)
typedef __attribute__((ext_vector_type(4))) float f32x4;    // MFMA accum

static __device__ __forceinline__ unsigned short f2bf(float f) {
  union { float f; unsigned u; } c; c.f = f;
  return (unsigned short)((c.u + 0x7fffu + ((c.u >> 16) & 1u)) >> 16);  // RNE
}

static __device__ __forceinline__ void gload_lds16(const void* g, void* l) {
  __builtin_amdgcn_global_load_lds(
      (const __attribute__((address_space(1))) void*)g,
      (__attribute__((address_space(3))) void*)l, 16, 0, 0);
}

// ---------------- prep: bf16 cast + row norms + pos term + rowMin init ------
__global__ __launch_bounds__(256) void prep_kernel(
    const float* __restrict__ o1, const float* __restrict__ o2,
    unsigned short* __restrict__ o1b, unsigned short* __restrict__ o2b,
    float* __restrict__ a2, float* __restrict__ b2, float* __restrict__ posr,
    unsigned int* __restrict__ rowMin, int* __restrict__ flag)
{
  const int row = blockIdx.x;
  const int t = threadIdx.x;
  const float4* p1 = (const float4*)(o1 + (size_t)row * DDIM);
  const float4* p2 = (const float4*)(o2 + (size_t)row * DDIM);
  float4 x1 = p1[t];
  float4 x2 = p2[t];
  float s1, s2, sp;
  {
    float a0 = x1.x, a1 = x1.y, aa2 = x1.z, a3 = x1.w;
    float b0 = x2.x, b1 = x2.y, bb2 = x2.z, b3 = x2.w;
    s1 = a0*a0 + a1*a1 + aa2*aa2 + a3*a3;
    s2 = b0*b0 + b1*b1 + bb2*bb2 + b3*b3;
    float d0 = b0-a0, d1 = b1-a1, d2 = bb2-aa2, d3 = b3-a3;
    sp = d0*d0 + d1*d1 + d2*d2 + d3*d3;
    *(ushort4*)(o1b + (size_t)row * DDIM + t * 4) =
        make_ushort4(f2bf(a0), f2bf(a1), f2bf(aa2), f2bf(a3));
    *(ushort4*)(o2b + (size_t)row * DDIM + t * 4) =
        make_ushort4(f2bf(b0), f2bf(b1), f2bf(bb2), f2bf(b3));
  }
  for (int s = 1; s < 64; s <<= 1) {
    s1 += __shfl_xor(s1, s);
    s2 += __shfl_xor(s2, s);
    sp += __shfl_xor(sp, s);
  }
  __shared__ float r1[4], r2[4], rp[4];
  const int wv = t >> 6;
  if ((t & 63) == 0) { r1[wv] = s1; r2[wv] = s2; rp[wv] = sp; }
  __syncthreads();
  if (t == 0) {
    a2[row]   = r1[0] + r1[1] + r1[2] + r1[3];
    b2[row]   = r2[0] + r2[1] + r2[2] + r2[3];
    posr[row] = rp[0] + rp[1] + rp[2] + rp[3];
    rowMin[row] = 0x7F800000u;           // +inf bits
    if (row == 0) *flag = 0;
  }
}

// ============================================================================
// Projection GEMM: proj[16384][64] = X[16384][1024] @ H^T, H = 64 Hadamard
// columns, entries ±1/32 (exactly orthonormal, exact in bf16). H fragments
// generated in registers (popcount sign). Also emits pnorm[i] = |proj_i|^2.
// M-tile 128, 4 waves x 32 rows, K-step 32. LDS swizzle: 4x16B slots/row,
// phys = slot ^ ((row>>1)&3), both-sides (pre-swizzled source, swizzled read).
// ============================================================================
__global__ __launch_bounds__(256) void proj_kernel(
    const unsigned short* __restrict__ X,   // o1b||o2b, 16384 x 1024 bf16
    unsigned short* __restrict__ proj,      // 16384 x 64 bf16
    float* __restrict__ pnorm)              // 16384
{
  __shared__ __align__(16) unsigned short lA[128 * 32];   // 8 KB
  const int tid  = threadIdx.x;
  const int lane = tid & 63;
  const int wave = tid >> 6;
  const int bm = blockIdx.x * 128;
  const int rlane = lane & 15;
  const int c32   = lane >> 4;

  // staging (R1 geometry + slot^((row>>1)&3) pre-swizzle on the SOURCE)
  const int stRow  = lane >> 2;                              // 16 rows/region
  const int stColH = ((lane & 3) ^ ((lane >> 3) & 3)) * 8;   // swizzled 16B slot
  const unsigned short* Ab = X + (size_t)bm * DDIM;

  // H fragments: B-frag lane layout col=lane&15, k=(lane>>4)*8+j; sign depends
  // only on k&63 -> two variants by kt parity.
  bf16x8 hf[2][4];
#pragma unroll
  for (int par = 0; par < 2; ++par)
#pragma unroll
    for (int ni = 0; ni < 4; ++ni) {
      const int p = ni * 16 + rlane;
      bf16x8 v;
#pragma unroll
      for (int j = 0; j < 8; ++j) {
        const int k = par * 32 + c32 * 8 + j;
        v[j] = (short)((__popc(p & k) & 1) ? 0xBD00 : 0x3D00);  // -+1/32
      }
      hf[par][ni] = v;
    }

  f32x4 acc[2][4];
#pragma unroll
  for (int mi = 0; mi < 2; ++mi)
#pragma unroll
    for (int ni = 0; ni < 4; ++ni) acc[mi][ni] = (f32x4)0.0f;

  const int kx = (rlane >> 1) & 3;            // read-side swizzle key
  const int rbase = (wave * 32 + rlane) * 64 + ((c32 ^ kx) * 16);  // bytes

  for (int kt = 0; kt < 32; ++kt) {
#pragma unroll
    for (int p = 0; p < 2; ++p) {
      const int off = (p * 4 + wave) * 1024;  // byte region: 16 rows x 64B
      const int r0  = off >> 6;
      gload_lds16(Ab + (size_t)(r0 + stRow) * DDIM + kt * 32 + stColH,
                  (char*)lA + off);
    }
    __syncthreads();
    bf16x8 af[2];
#pragma unroll
    for (int mi = 0; mi < 2; ++mi)
      af[mi] = *(const bf16x8*)((const char*)lA + rbase + mi * 1024);
#pragma unroll
    for (int mi = 0; mi < 2; ++mi)
#pragma unroll
      for (int ni = 0; ni < 4; ++ni)
        acc[mi][ni] = __builtin_amdgcn_mfma_f32_16x16x32_bf16(
            af[mi], hf[kt & 1][ni], acc[mi][ni], 0, 0, 0);
    __syncthreads();
  }

  // epilogue: store proj (bf16) + pnorm. C/D: col=lane&15, row=(lane>>4)*4+j.
#pragma unroll
  for (int mi = 0; mi < 2; ++mi) {
#pragma unroll
    for (int j = 0; j < 4; ++j) {
      const int row = bm + wave * 32 + mi * 16 + (c32 << 2) + j;
      float s = 0.0f;
#pragma unroll
      for (int ni = 0; ni < 4; ++ni) {
        const float v = acc[mi][ni][j];
        s += v * v;
        proj[(size_t)row * NPROJ + ni * 16 + rlane] = f2bf(v);
      }
#pragma unroll
      for (int m = 1; m < 16; m <<= 1) s += __shfl_xor(s, m);
      if (rlane == 0) pnorm[row] = s;
    }
  }
}

// ============================================================================
// K=64 gram of projections -> rowMin of the CERTIFIED LOWER BOUND
// sq64(i,j) = pn[i]+pn[j']-2*projA_i . projB_j  (Bessel: sq64 <= true sq).
// 128x128 tile, 4 waves 2x2, no K-loop (one stage, 2 k-steps, 32 MFMA).
// LDS swizzle: 8x16B slots/row, phys = slot ^ (row&7), both-sides.
// ============================================================================
__global__ __launch_bounds__(256) void gram64_kernel(
    const unsigned short* __restrict__ P,   // proj: 16384 x 64 bf16
    const float* __restrict__ pn,           // 16384
    unsigned int* __restrict__ rowMin)
{
  __shared__ __align__(16) unsigned short lA[128 * 64];   // 16 KB
  __shared__ __align__(16) unsigned short lB[128 * 64];   // 16 KB
  const int tid  = threadIdx.x;
  const int lane = tid & 63;
  const int wave = tid >> 6;
  const int bm = blockIdx.y * 128;
  const int bn = blockIdx.x * 128;
  const int wm = (wave >> 1) * 64;
  const int wn = (wave & 1) * 64;
  const int rlane = lane & 15;
  const int c32   = lane >> 4;

  const int srow  = tid >> 3;                      // 0..31
  const int sslot = (tid & 7) ^ (srow & 7);        // pre-swizzled source slot
  const unsigned short* Asrc = P + (size_t)(bm + srow) * NPROJ + sslot * 8;
  const unsigned short* Bsrc = P + (size_t)(NROWS + bn + srow) * NPROJ + sslot * 8;
#pragma unroll
  for (int q = 0; q < 4; ++q) {
    gload_lds16(Asrc + (size_t)q * 32 * NPROJ, (char*)lA + q * 4096 + tid * 16);
    gload_lds16(Bsrc + (size_t)q * 32 * NPROJ, (char*)lB + q * 4096 + tid * 16);
  }
  __syncthreads();

  f32x4 acc[4][4];
#pragma unroll
  for (int mi = 0; mi < 4; ++mi)
#pragma unroll
    for (int ni = 0; ni < 4; ++ni) acc[mi][ni] = (f32x4)0.0f;

#pragma unroll
  for (int ks = 0; ks < 2; ++ks) {
    bf16x8 af[4], bfr[4];
#pragma unroll
    for (int mi = 0; mi < 4; ++mi) {
      const int r = wm + mi * 16 + rlane;
      const int phys = (ks * 4 + c32) ^ (r & 7);
      af[mi] = *(const bf16x8*)((const char*)lA + r * 128 + phys * 16);
    }
#pragma unroll
    for (int ni = 0; ni < 4; ++ni) {
      const int r = wn + ni * 16 + rlane;
      const int phys = (ks * 4 + c32) ^ (r & 7);
      bfr[ni] = *(const bf16x8*)((const char*)lB + r * 128 + phys * 16);
    }
#pragma unroll
    for (int mi = 0; mi < 4; ++mi)
#pragma unroll
      for (int ni = 0; ni < 4; ++ni)
        acc[mi][ni] = __builtin_amdgcn_mfma_f32_16x16x32_bf16(
            af[mi], bfr[ni], acc[mi][ni], 0, 0, 0);
  }

  // epilogue: rowMin of clamped lower bound
#pragma unroll
  for (int mi = 0; mi < 4; ++mi) {
#pragma unroll
    for (int j = 0; j < 4; ++j) {
      const int i = bm + wm + mi * 16 + (c32 << 2) + j;
      const float av = pn[i];
      float mn = __builtin_inff();
#pragma unroll
      for (int ni = 0; ni < 4; ++ni) {
        const int jj = bn + wn + ni * 16 + rlane;
        mn = fminf(mn, av + pn[NROWS + jj] - 2.0f * acc[mi][ni][j]);
      }
#pragma unroll
      for (int s = 1; s < 16; s <<= 1) mn = fminf(mn, __shfl_xor(mn, s));
      if (rlane == 0) atomicMin(&rowMin[i], __float_as_uint(fmaxf(mn, 0.0f)));
    }
  }
}

// ---------------- flag: any row with lower-bound min < 16 (dist < 4)? -------
// True dist<2 pair implies bound < ~7.1 incl. all rounding -> always caught.
// Benign data: bound ~ 2*chi2_64, P(<16) ~ 1e-21 -> never fires.
__global__ __launch_bounds__(256) void flag_kernel(const unsigned int* __restrict__ rowMin,
                                                   int* __restrict__ flag)
{
  const int i = blockIdx.x * 256 + threadIdx.x;
  if (i < NROWS && rowMin[i] < 0x41800000u /* bits(16.0f) */) atomicExch(flag, 1);
}

// ---------------- 128^2 bf16 GEMM (flag-gated exact-path sq store) ----------
template<int STORE_SQ>
__global__ __launch_bounds__(256) void gemm_kernel(
    const unsigned short* __restrict__ A, const unsigned short* __restrict__ B,
    const float* __restrict__ a2, const float* __restrict__ b2,
    unsigned int* __restrict__ rowMin, const int* __restrict__ flag,
    float* __restrict__ sqbuf, int jBase, int chunkCols)
{
  if (STORE_SQ) { if (*flag == 0) return; }   // never taken on benign data
  __shared__ __align__(16) unsigned short lA[128 * 32];
  __shared__ __align__(16) unsigned short lB[128 * 32];
  const int tid  = threadIdx.x;
  const int lane = tid & 63;
  const int wave = tid >> 6;
  const int bm = blockIdx.y * 128;
  const int bn = blockIdx.x * 128;
  const int wm = (wave >> 1) * 64;
  const int wn = (wave & 1) * 64;

  f32x4 acc[4][4];
#pragma unroll
  for (int mi = 0; mi < 4; ++mi)
#pragma unroll
    for (int ni = 0; ni < 4; ++ni)
      acc[mi][ni] = (f32x4)0.0f;

  const unsigned short* Ab = A + (size_t)bm * DDIM;
  const unsigned short* Bb = B + (size_t)(jBase + bn) * DDIM;
  const int stRow  = lane >> 2;
  const int stColH = (lane & 3) * 8;

  for (int kt = 0; kt < DDIM / 32; ++kt) {
#pragma unroll
    for (int p = 0; p < 2; ++p) {
      const int off = (p * 4 + wave) * 1024;
      const int r0  = off >> 6;
      gload_lds16(Ab + (size_t)(r0 + stRow) * DDIM + kt * 32 + stColH, (char*)lA + off);
      gload_lds16(Bb + (size_t)(r0 + stRow) * DDIM + kt * 32 + stColH, (char*)lB + off);
    }
    __syncthreads();

    bf16x8 af[4], bfr[4];
#pragma unroll
    for (int mi = 0; mi < 4; ++mi) {
      const int r = wm + mi * 16 + (lane & 15);
      af[mi] = *(const bf16x8*)((const char*)lA + r * 64 + (lane >> 4) * 16);
    }
#pragma unroll
    for (int ni = 0; ni < 4; ++ni) {
      const int r = wn + ni * 16 + (lane & 15);
      bfr[ni] = *(const bf16x8*)((const char*)lB + r * 64 + (lane >> 4) * 16);
    }
#pragma unroll
    for (int mi = 0; mi < 4; ++mi)
#pragma unroll
      for (int ni = 0; ni < 4; ++ni)
        acc[mi][ni] = __builtin_amdgcn_mfma_f32_16x16x32_bf16(af[mi], bfr[ni], acc[mi][ni], 0, 0, 0);
    __syncthreads();
  }

  if (STORE_SQ == 0) {
#pragma unroll
    for (int mi = 0; mi < 4; ++mi) {
#pragma unroll
      for (int j = 0; j < 4; ++j) {
        const int i = bm + wm + mi * 16 + ((lane >> 4) << 2) + j;
        const float av = a2[i];
        float mn = __builtin_inff();
#pragma unroll
        for (int ni = 0; ni < 4; ++ni) {
          const int jj = bn + wn + ni * 16 + (lane & 15);
          mn = fminf(mn, av + b2[jj] - 2.0f * acc[mi][ni][j]);
        }
#pragma unroll
        for (int s = 1; s < 16; s <<= 1) mn = fminf(mn, __shfl_xor(mn, s));
        if ((lane & 15) == 0) atomicMin(&rowMin[i], __float_as_uint(fmaxf(mn, 0.0f)));
      }
    }
  } else {
#pragma unroll
    for (int mi = 0; mi < 4; ++mi) {
#pragma unroll
      for (int j = 0; j < 4; ++j) {
        const int i = bm + wm + mi * 16 + ((lane >> 4) << 2) + j;
        const float av = a2[i];
#pragma unroll
        for (int ni = 0; ni < 4; ++ni) {
          const int jj = bn + wn + ni * 16 + (lane & 15);
          sqbuf[(size_t)i * chunkCols + jj] = av + b2[jBase + jj] - 2.0f * acc[mi][ni][j];
        }
      }
    }
  }
}

// ---------------- exact top-30 per row (fallback; flag-gated) ---------------
template<int VPL>
__global__ __launch_bounds__(64) void select_kernel(
    const float* __restrict__ sqbuf, const int* __restrict__ flag,
    float* __restrict__ tv, int* __restrict__ ti, int jBase, int isFirst)
{
  if (*flag == 0) return;
  const int row = blockIdx.x, lane = threadIdx.x;
  const int CH = VPL * 64;
  float v[VPL];
#pragma unroll
  for (int q = 0; q < VPL; ++q)
    v[q] = sqbuf[(size_t)row * CH + q * 64 + lane];
  float cv; int ci;
  if (isFirst) { cv = __builtin_inff(); ci = 0x7fffffff; }
  else {
    cv = (lane < NQ) ? tv[row * 32 + lane] : __builtin_inff();
    ci = (lane < NQ) ? ti[row * 32 + lane] : 0x7fffffff;
  }
  for (int k = 0; k < NQ; ++k) {
    float mv = cv; int mi_ = ci;
#pragma unroll
    for (int q = 0; q < VPL; ++q) {
      const int col = jBase + q * 64 + lane;
      const bool b = (v[q] < mv) || (v[q] == mv && col < mi_);
      mv  = b ? v[q] : mv;
      mi_ = b ? col  : mi_;
    }
#pragma unroll
    for (int s = 1; s < 64; s <<= 1) {
      const float ov = __shfl_xor(mv, s);
      const int   oi = __shfl_xor(mi_, s);
      const bool b = (ov < mv) || (ov == mv && oi < mi_);
      mv  = b ? ov : mv;
      mi_ = b ? oi : mi_;
    }
    if (mi_ == ci) cv = __builtin_inff();
    else if (mi_ >= jBase) {
      const int rel = mi_ - jBase;
      if ((rel & 63) == lane) {
        const int lq = rel >> 6;
#pragma unroll
        for (int q = 0; q < VPL; ++q) if (q == lq) v[q] = __builtin_inff();
      }
    }
    if (lane == 0) { tv[row * 32 + k] = mv; ti[row * 32 + k] = mi_; }
  }
}

// ---------------- final reduction ------------------------------------------
__global__ __launch_bounds__(256) void final_kernel(
    const float* __restrict__ posr, const float* __restrict__ tv,
    const int* __restrict__ ti, const int* __restrict__ rn,
    const int* __restrict__ flag, float* __restrict__ out)
{
  const int t = threadIdx.x;
  const int useNeg = (*flag != 0);
  double ps = 0.0, ns = 0.0;
  for (int r = t; r < NROWS; r += 256) {
    ps += (double)posr[r];
    if (useNeg) {
      int k = rn[r];
      const int sel = ti[r * 32 + k];
      if (sel == r) k = (k + 1) % NQ;
      const float d = sqrtf(fmaxf(tv[r * 32 + k], 0.0f));
      ns += (double)fmaxf(MARGINF - d, 0.0f);
    }
  }
  __shared__ double sp[256], sn[256];
  sp[t] = ps; sn[t] = ns;
  __syncthreads();
  for (int s = 128; s > 0; s >>= 1) {
    if (t < s) { sp[t] += sp[t + s]; sn[t] += sn[t + s]; }
    __syncthreads();
  }
  if (t == 0) out[0] = (float)(sp[0] / NROWS + sn[0] / NROWS);
}

extern "C" void kernel_launch(void* const* d_in, const int* in_sizes, int n_in,
                              void* d_out, int out_size, void* d_ws, size_t ws_size,
                              hipStream_t stream) {
  (void)in_sizes; (void)n_in; (void)out_size;
  const float* o1 = (const float*)d_in[0];
  const float* o2 = (const float*)d_in[1];
  const int*   rn = (const int*)d_in[2];
  float* out = (float*)d_out;

  char* ws = (char*)d_ws;
  size_t off = 0;
  auto alloc = [&](size_t b) { void* p = ws + off; off += (b + 255) & ~(size_t)255; return p; };
  unsigned short* o1b = (unsigned short*)alloc((size_t)NROWS * DDIM * 2);  // 16 MB
  unsigned short* o2b = (unsigned short*)alloc((size_t)NROWS * DDIM * 2);  // 16 MB (contiguous after o1b)
  float* a2   = (float*)alloc((size_t)NROWS * 4);
  float* b2   = (float*)alloc((size_t)NROWS * 4);
  float* posr = (float*)alloc((size_t)NROWS * 4);
  unsigned int* rowMin = (unsigned int*)alloc((size_t)NROWS * 4);
  int*   flag = (int*)alloc(256);
  float* tv   = (float*)alloc((size_t)NROWS * 32 * 4);
  int*   ti   = (int*)alloc((size_t)NROWS * 32 * 4);
  unsigned short* proj = (unsigned short*)alloc((size_t)2 * NROWS * NPROJ * 2);  // 2 MB
  float* pnorm = (float*)alloc((size_t)2 * NROWS * 4);                           // 128 KB
  const size_t remain = ws_size > off ? ws_size - off : 0;
  int chunk;
  if      (remain >= (size_t)NROWS * 8192 * 4) chunk = 8192;
  else if (remain >= (size_t)NROWS * 2048 * 4) chunk = 2048;
  else if (remain >= (size_t)NROWS * 512 * 4)  chunk = 512;
  else                                         chunk = 128;
  float* sqbuf = (float*)(ws + off);

  prep_kernel<<<NROWS, 256, 0, stream>>>(o1, o2, o1b, o2b, a2, b2, posr, rowMin, flag);
  proj_kernel<<<2 * NROWS / 128, 256, 0, stream>>>(o1b, proj, pnorm);
  gram64_kernel<<<dim3(64, 64), 256, 0, stream>>>(proj, pnorm, rowMin);
  flag_kernel<<<dim3(NROWS / 256), 256, 0, stream>>>(rowMin, flag);

  const int nch = NROWS / chunk;
  for (int c = 0; c < nch; ++c) {
    gemm_kernel<1><<<dim3(chunk / 128, 64), 256, 0, stream>>>(o1b, o2b, a2, b2, rowMin, flag,
                                                              sqbuf, c * chunk, chunk);
    const int first = (c == 0);
    if      (chunk == 8192) select_kernel<128><<<NROWS, 64, 0, stream>>>(sqbuf, flag, tv, ti, c * chunk, first);
    else if (chunk == 2048) select_kernel<32><<<NROWS, 64, 0, stream>>>(sqbuf, flag, tv, ti, c * chunk, first);
    else if (chunk == 512)  select_kernel<8><<<NROWS, 64, 0, stream>>>(sqbuf, flag, tv, ti, c * chunk, first);
    else                    select_kernel<2><<<NROWS, 64, 0, stream>>>(sqbuf, flag, tv, ti, c * chunk, first);
  }
  final_kernel<<<1, 256, 0, stream>>>(posr, tv, ti, rn, flag, out);
}

// Round 7
// 109.305 us; speedup vs baseline: 11.5275x; 1.2767x over previous
//
#include <hip/hip_runtime.h>
#include <hip/hip_bf16.h>
#include <stdint.h>

#define NROWS 8192
#define DDIM  1024
#define NQ    30
#define MARGINF 2.0f
#define NPROJ 64

typedef __attribute__((ext_vector_type(8))) short bf16x8;   // 8 bf16 (4 VGPRs)
typedef __attribute__((ext_vector_type(4))) float f32x4;    // MFMA accum

static __device__ __forceinline__ unsigned short f2bf(float f) {
  union { float f; unsigned u; } c; c.f = f;
  return (unsigned short)((c.u + 0x7fffu + ((c.u >> 16) & 1u)) >> 16);  // RNE
}

static __device__ __forceinline__ void gload_lds16(const void* g, void* l) {
  __builtin_amdgcn_global_load_lds(
      (const __attribute__((address_space(1))) void*)g,
      (__attribute__((address_space(3))) void*)l, 16, 0, 0);
}

// ---------------- prep: bf16 cast + row norms + pos term + rowMin init ------
__global__ __launch_bounds__(256) void prep_kernel(
    const float* __restrict__ o1, const float* __restrict__ o2,
    unsigned short* __restrict__ o1b, unsigned short* __restrict__ o2b,
    float* __restrict__ a2, float* __restrict__ b2, float* __restrict__ posr,
    unsigned int* __restrict__ rowMin, int* __restrict__ flag)
{
  const int row = blockIdx.x;
  const int t = threadIdx.x;
  const float4* p1 = (const float4*)(o1 + (size_t)row * DDIM);
  const float4* p2 = (const float4*)(o2 + (size_t)row * DDIM);
  float4 x1 = p1[t];
  float4 x2 = p2[t];
  float s1, s2, sp;
  {
    float a0 = x1.x, a1 = x1.y, aa2 = x1.z, a3 = x1.w;
    float b0 = x2.x, b1 = x2.y, bb2 = x2.z, b3 = x2.w;
    s1 = a0*a0 + a1*a1 + aa2*aa2 + a3*a3;
    s2 = b0*b0 + b1*b1 + bb2*bb2 + b3*b3;
    float d0 = b0-a0, d1 = b1-a1, d2 = bb2-aa2, d3 = b3-a3;
    sp = d0*d0 + d1*d1 + d2*d2 + d3*d3;
    *(ushort4*)(o1b + (size_t)row * DDIM + t * 4) =
        make_ushort4(f2bf(a0), f2bf(a1), f2bf(aa2), f2bf(a3));
    *(ushort4*)(o2b + (size_t)row * DDIM + t * 4) =
        make_ushort4(f2bf(b0), f2bf(b1), f2bf(bb2), f2bf(b3));
  }
  for (int s = 1; s < 64; s <<= 1) {
    s1 += __shfl_xor(s1, s);
    s2 += __shfl_xor(s2, s);
    sp += __shfl_xor(sp, s);
  }
  __shared__ float r1[4], r2[4], rp[4];
  const int wv = t >> 6;
  if ((t & 63) == 0) { r1[wv] = s1; r2[wv] = s2; rp[wv] = sp; }
  __syncthreads();
  if (t == 0) {
    a2[row]   = r1[0] + r1[1] + r1[2] + r1[3];
    b2[row]   = r2[0] + r2[1] + r2[2] + r2[3];
    posr[row] = rp[0] + rp[1] + rp[2] + rp[3];
    rowMin[row] = 0x7F800000u;           // +inf bits
    if (row == 0) *flag = 0;
  }
}

// ============================================================================
// Projection GEMM: proj[16384][64] = X[16384][1024] @ H^T, H = 64 Hadamard
// columns, entries ±1/32 (exactly orthonormal, exact in bf16). H fragments
// generated in registers (popcount sign). Also emits pnorm[i] = |proj_i|^2.
// ============================================================================
__global__ __launch_bounds__(256) void proj_kernel(
    const unsigned short* __restrict__ X,   // o1b||o2b, 16384 x 1024 bf16
    unsigned short* __restrict__ proj,      // 16384 x 64 bf16
    float* __restrict__ pnorm)              // 16384
{
  __shared__ __align__(16) unsigned short lA[128 * 32];   // 8 KB
  const int tid  = threadIdx.x;
  const int lane = tid & 63;
  const int wave = tid >> 6;
  const int bm = blockIdx.x * 128;
  const int rlane = lane & 15;
  const int c32   = lane >> 4;

  // staging (R1 geometry + slot^((row>>1)&3) pre-swizzle on the SOURCE)
  const int stRow  = lane >> 2;                              // 16 rows/region
  const int stColH = ((lane & 3) ^ ((lane >> 3) & 3)) * 8;   // swizzled 16B slot
  const unsigned short* Ab = X + (size_t)bm * DDIM;

  // H fragments: B-frag lane layout col=lane&15, k=(lane>>4)*8+j; sign depends
  // only on k&63 -> two variants by kt parity.
  bf16x8 hf[2][4];
#pragma unroll
  for (int par = 0; par < 2; ++par)
#pragma unroll
    for (int ni = 0; ni < 4; ++ni) {
      const int p = ni * 16 + rlane;
      bf16x8 v;
#pragma unroll
      for (int j = 0; j < 8; ++j) {
        const int k = par * 32 + c32 * 8 + j;
        v[j] = (short)((__popc(p & k) & 1) ? 0xBD00 : 0x3D00);  // -+1/32
      }
      hf[par][ni] = v;
    }

  f32x4 acc[2][4];
#pragma unroll
  for (int mi = 0; mi < 2; ++mi)
#pragma unroll
    for (int ni = 0; ni < 4; ++ni) acc[mi][ni] = (f32x4)0.0f;

  const int kx = (rlane >> 1) & 3;            // read-side swizzle key
  const int rbase = (wave * 32 + rlane) * 64 + ((c32 ^ kx) * 16);  // bytes

  for (int kt = 0; kt < 32; ++kt) {
#pragma unroll
    for (int p = 0; p < 2; ++p) {
      const int off = (p * 4 + wave) * 1024;  // byte region: 16 rows x 64B
      const int r0  = off >> 6;
      gload_lds16(Ab + (size_t)(r0 + stRow) * DDIM + kt * 32 + stColH,
                  (char*)lA + off);
    }
    __syncthreads();
    bf16x8 af[2];
#pragma unroll
    for (int mi = 0; mi < 2; ++mi)
      af[mi] = *(const bf16x8*)((const char*)lA + rbase + mi * 1024);
#pragma unroll
    for (int mi = 0; mi < 2; ++mi)
#pragma unroll
      for (int ni = 0; ni < 4; ++ni)
        acc[mi][ni] = __builtin_amdgcn_mfma_f32_16x16x32_bf16(
            af[mi], hf[kt & 1][ni], acc[mi][ni], 0, 0, 0);
    __syncthreads();
  }

  // epilogue: store proj (bf16) + pnorm. C/D: col=lane&15, row=(lane>>4)*4+j.
#pragma unroll
  for (int mi = 0; mi < 2; ++mi) {
#pragma unroll
    for (int j = 0; j < 4; ++j) {
      const int row = bm + wave * 32 + mi * 16 + (c32 << 2) + j;
      float s = 0.0f;
#pragma unroll
      for (int ni = 0; ni < 4; ++ni) {
        const float v = acc[mi][ni][j];
        s += v * v;
        proj[(size_t)row * NPROJ + ni * 16 + rlane] = f2bf(v);
      }
#pragma unroll
      for (int m = 1; m < 16; m <<= 1) s += __shfl_xor(s, m);
      if (rlane == 0) pnorm[row] = s;
    }
  }
}

// ============================================================================
// K=64 gram of projections -> rowMin of the CERTIFIED LOWER BOUND.
// Register-direct (no LDS, no barriers): proj is 4 MB, L2-resident; each
// fragment is ONE 16B global load at a static address. Grid 64x8 = 512
// blocks; block sweeps 8 B-tiles (128x1024 output), A-frags loaded once,
// B-frags double-buffered (static names, rule #20), per-lane running min
// -> one atomicMin per row per wave-col (131k atomics vs 1M before).
// Fragment math identical to the R1-validated pattern:
//   frag(row, ks) = 16B at P[row*64 + ks*32 + c32*8] (ushort units).
// ============================================================================
__global__ __launch_bounds__(256) void gram64_kernel(
    const unsigned short* __restrict__ P,   // proj: 16384 x 64 bf16
    const float* __restrict__ pn,           // 16384
    unsigned int* __restrict__ rowMin)
{
  const int tid  = threadIdx.x;
  const int lane = tid & 63;
  const int wave = tid >> 6;
  const int bm = blockIdx.x * 128;        // 64 M-tiles
  const int bg = blockIdx.y * 1024;       // 8 N-groups of 8x128 cols
  const int wm = (wave >> 1) * 64;
  const int wn = (wave & 1) * 64;
  const int rlane = lane & 15;
  const int c32   = lane >> 4;

  // A fragments, loaded once (L2-hit)
  bf16x8 af[4][2];
#pragma unroll
  for (int mi = 0; mi < 4; ++mi)
#pragma unroll
    for (int ks = 0; ks < 2; ++ks)
      af[mi][ks] = *(const bf16x8*)(
          P + (size_t)(bm + wm + mi * 16 + rlane) * NPROJ + ks * 32 + c32 * 8);

  float rmn[4][4];
#pragma unroll
  for (int mi = 0; mi < 4; ++mi)
#pragma unroll
    for (int j = 0; j < 4; ++j) rmn[mi][j] = __builtin_inff();

#define LOADB(buf, pnv, t) do { \
    const int bn_ = bg + (t) * 128 + wn; \
    _Pragma("unroll") for (int ni = 0; ni < 4; ++ni) { \
      _Pragma("unroll") for (int ks = 0; ks < 2; ++ks) \
        buf[ni][ks] = *(const bf16x8*)( \
            P + (size_t)(NROWS + bn_ + ni * 16 + rlane) * NPROJ + ks * 32 + c32 * 8); \
      pnv[ni] = pn[NROWS + bn_ + ni * 16 + rlane]; \
    } \
  } while (0)

#define COMPUTE(buf, pnv) do { \
    f32x4 acc[4][4]; \
    _Pragma("unroll") for (int mi = 0; mi < 4; ++mi) \
    _Pragma("unroll") for (int ni = 0; ni < 4; ++ni) acc[mi][ni] = (f32x4)0.0f; \
    _Pragma("unroll") for (int mi = 0; mi < 4; ++mi) \
    _Pragma("unroll") for (int ni = 0; ni < 4; ++ni) \
    _Pragma("unroll") for (int ks = 0; ks < 2; ++ks) \
      acc[mi][ni] = __builtin_amdgcn_mfma_f32_16x16x32_bf16( \
          af[mi][ks], buf[ni][ks], acc[mi][ni], 0, 0, 0); \
    _Pragma("unroll") for (int mi = 0; mi < 4; ++mi) \
    _Pragma("unroll") for (int j = 0; j < 4; ++j) \
    _Pragma("unroll") for (int ni = 0; ni < 4; ++ni) \
      rmn[mi][j] = fminf(rmn[mi][j], pnv[ni] - 2.0f * acc[mi][ni][j]); \
  } while (0)

  bf16x8 bfA[4][2], bfB[4][2];
  float pnA[4], pnB[4];
  LOADB(bfA, pnA, 0);
#pragma unroll
  for (int t = 0; t < 8; t += 2) {
    LOADB(bfB, pnB, t + 1);       // prefetch odd tile
    COMPUTE(bfA, pnA);
    if (t + 2 < 8) LOADB(bfA, pnA, t + 2);  // prefetch next even tile
    COMPUTE(bfB, pnB);
  }
#undef LOADB
#undef COMPUTE

  // epilogue: bound = pn[row] + min(pnB - 2*gram); C/D row=(lane>>4)*4+j
#pragma unroll
  for (int mi = 0; mi < 4; ++mi) {
#pragma unroll
    for (int j = 0; j < 4; ++j) {
      const int row = bm + wm + mi * 16 + (c32 << 2) + j;
      float mn = rmn[mi][j] + pn[row];
#pragma unroll
      for (int s = 1; s < 16; s <<= 1) mn = fminf(mn, __shfl_xor(mn, s));
      if (rlane == 0) atomicMin(&rowMin[row], __float_as_uint(fmaxf(mn, 0.0f)));
    }
  }
}

// ---------------- flag: any row with lower-bound min < 16 (dist < 4)? -------
// True dist<2 pair implies bound < ~7.1 incl. all rounding -> always caught.
// Benign data: bound ~ 2*chi2_64, P(<16) ~ 1e-21 -> never fires.
__global__ __launch_bounds__(256) void flag_kernel(const unsigned int* __restrict__ rowMin,
                                                   int* __restrict__ flag)
{
  const int i = blockIdx.x * 256 + threadIdx.x;
  if (i < NROWS && rowMin[i] < 0x41800000u /* bits(16.0f) */) atomicExch(flag, 1);
}

// ---------------- 128^2 bf16 GEMM (flag-gated exact-path sq store) ----------
template<int STORE_SQ>
__global__ __launch_bounds__(256) void gemm_kernel(
    const unsigned short* __restrict__ A, const unsigned short* __restrict__ B,
    const float* __restrict__ a2, const float* __restrict__ b2,
    unsigned int* __restrict__ rowMin, const int* __restrict__ flag,
    float* __restrict__ sqbuf, int jBase, int chunkCols)
{
  if (STORE_SQ) { if (*flag == 0) return; }   // never taken on benign data
  __shared__ __align__(16) unsigned short lA[128 * 32];
  __shared__ __align__(16) unsigned short lB[128 * 32];
  const int tid  = threadIdx.x;
  const int lane = tid & 63;
  const int wave = tid >> 6;
  const int bm = blockIdx.y * 128;
  const int bn = blockIdx.x * 128;
  const int wm = (wave >> 1) * 64;
  const int wn = (wave & 1) * 64;

  f32x4 acc[4][4];
#pragma unroll
  for (int mi = 0; mi < 4; ++mi)
#pragma unroll
    for (int ni = 0; ni < 4; ++ni)
      acc[mi][ni] = (f32x4)0.0f;

  const unsigned short* Ab = A + (size_t)bm * DDIM;
  const unsigned short* Bb = B + (size_t)(jBase + bn) * DDIM;
  const int stRow  = lane >> 2;
  const int stColH = (lane & 3) * 8;

  for (int kt = 0; kt < DDIM / 32; ++kt) {
#pragma unroll
    for (int p = 0; p < 2; ++p) {
      const int off = (p * 4 + wave) * 1024;
      const int r0  = off >> 6;
      gload_lds16(Ab + (size_t)(r0 + stRow) * DDIM + kt * 32 + stColH, (char*)lA + off);
      gload_lds16(Bb + (size_t)(r0 + stRow) * DDIM + kt * 32 + stColH, (char*)lB + off);
    }
    __syncthreads();

    bf16x8 af[4], bfr[4];
#pragma unroll
    for (int mi = 0; mi < 4; ++mi) {
      const int r = wm + mi * 16 + (lane & 15);
      af[mi] = *(const bf16x8*)((const char*)lA + r * 64 + (lane >> 4) * 16);
    }
#pragma unroll
    for (int ni = 0; ni < 4; ++ni) {
      const int r = wn + ni * 16 + (lane & 15);
      bfr[ni] = *(const bf16x8*)((const char*)lB + r * 64 + (lane >> 4) * 16);
    }
#pragma unroll
    for (int mi = 0; mi < 4; ++mi)
#pragma unroll
      for (int ni = 0; ni < 4; ++ni)
        acc[mi][ni] = __builtin_amdgcn_mfma_f32_16x16x32_bf16(af[mi], bfr[ni], acc[mi][ni], 0, 0, 0);
    __syncthreads();
  }

  if (STORE_SQ == 0) {
#pragma unroll
    for (int mi = 0; mi < 4; ++mi) {
#pragma unroll
      for (int j = 0; j < 4; ++j) {
        const int i = bm + wm + mi * 16 + ((lane >> 4) << 2) + j;
        const float av = a2[i];
        float mn = __builtin_inff();
#pragma unroll
        for (int ni = 0; ni < 4; ++ni) {
          const int jj = bn + wn + ni * 16 + (lane & 15);
          mn = fminf(mn, av + b2[jj] - 2.0f * acc[mi][ni][j]);
        }
#pragma unroll
        for (int s = 1; s < 16; s <<= 1) mn = fminf(mn, __shfl_xor(mn, s));
        if ((lane & 15) == 0) atomicMin(&rowMin[i], __float_as_uint(fmaxf(mn, 0.0f)));
      }
    }
  } else {
#pragma unroll
    for (int mi = 0; mi < 4; ++mi) {
#pragma unroll
      for (int j = 0; j < 4; ++j) {
        const int i = bm + wm + mi * 16 + ((lane >> 4) << 2) + j;
        const float av = a2[i];
#pragma unroll
        for (int ni = 0; ni < 4; ++ni) {
          const int jj = bn + wn + ni * 16 + (lane & 15);
          sqbuf[(size_t)i * chunkCols + jj] = av + b2[jBase + jj] - 2.0f * acc[mi][ni][j];
        }
      }
    }
  }
}

// ---------------- exact top-30 per row (fallback; flag-gated) ---------------
template<int VPL>
__global__ __launch_bounds__(64) void select_kernel(
    const float* __restrict__ sqbuf, const int* __restrict__ flag,
    float* __restrict__ tv, int* __restrict__ ti, int jBase, int isFirst)
{
  if (*flag == 0) return;
  const int row = blockIdx.x, lane = threadIdx.x;
  const int CH = VPL * 64;
  float v[VPL];
#pragma unroll
  for (int q = 0; q < VPL; ++q)
    v[q] = sqbuf[(size_t)row * CH + q * 64 + lane];
  float cv; int ci;
  if (isFirst) { cv = __builtin_inff(); ci = 0x7fffffff; }
  else {
    cv = (lane < NQ) ? tv[row * 32 + lane] : __builtin_inff();
    ci = (lane < NQ) ? ti[row * 32 + lane] : 0x7fffffff;
  }
  for (int k = 0; k < NQ; ++k) {
    float mv = cv; int mi_ = ci;
#pragma unroll
    for (int q = 0; q < VPL; ++q) {
      const int col = jBase + q * 64 + lane;
      const bool b = (v[q] < mv) || (v[q] == mv && col < mi_);
      mv  = b ? v[q] : mv;
      mi_ = b ? col  : mi_;
    }
#pragma unroll
    for (int s = 1; s < 64; s <<= 1) {
      const float ov = __shfl_xor(mv, s);
      const int   oi = __shfl_xor(mi_, s);
      const bool b = (ov < mv) || (ov == mv && oi < mi_);
      mv  = b ? ov : mv;
      mi_ = b ? oi : mi_;
    }
    if (mi_ == ci) cv = __builtin_inff();
    else if (mi_ >= jBase) {
      const int rel = mi_ - jBase;
      if ((rel & 63) == lane) {
        const int lq = rel >> 6;
#pragma unroll
        for (int q = 0; q < VPL; ++q) if (q == lq) v[q] = __builtin_inff();
      }
    }
    if (lane == 0) { tv[row * 32 + k] = mv; ti[row * 32 + k] = mi_; }
  }
}

// ---------------- final reduction ------------------------------------------
__global__ __launch_bounds__(256) void final_kernel(
    const float* __restrict__ posr, const float* __restrict__ tv,
    const int* __restrict__ ti, const int* __restrict__ rn,
    const int* __restrict__ flag, float* __restrict__ out)
{
  const int t = threadIdx.x;
  const int useNeg = (*flag != 0);
  double ps = 0.0, ns = 0.0;
  for (int r = t; r < NROWS; r += 256) {
    ps += (double)posr[r];
    if (useNeg) {
      int k = rn[r];
      const int sel = ti[r * 32 + k];
      if (sel == r) k = (k + 1) % NQ;
      const float d = sqrtf(fmaxf(tv[r * 32 + k], 0.0f));
      ns += (double)fmaxf(MARGINF - d, 0.0f);
    }
  }
  __shared__ double sp[256], sn[256];
  sp[t] = ps; sn[t] = ns;
  __syncthreads();
  for (int s = 128; s > 0; s >>= 1) {
    if (t < s) { sp[t] += sp[t + s]; sn[t] += sn[t + s]; }
    __syncthreads();
  }
  if (t == 0) out[0] = (float)(sp[0] / NROWS + sn[0] / NROWS);
}

extern "C" void kernel_launch(void* const* d_in, const int* in_sizes, int n_in,
                              void* d_out, int out_size, void* d_ws, size_t ws_size,
                              hipStream_t stream) {
  (void)in_sizes; (void)n_in; (void)out_size;
  const float* o1 = (const float*)d_in[0];
  const float* o2 = (const float*)d_in[1];
  const int*   rn = (const int*)d_in[2];
  float* out = (float*)d_out;

  char* ws = (char*)d_ws;
  size_t off = 0;
  auto alloc = [&](size_t b) { void* p = ws + off; off += (b + 255) & ~(size_t)255; return p; };
  unsigned short* o1b = (unsigned short*)alloc((size_t)NROWS * DDIM * 2);  // 16 MB
  unsigned short* o2b = (unsigned short*)alloc((size_t)NROWS * DDIM * 2);  // 16 MB (contiguous after o1b)
  float* a2   = (float*)alloc((size_t)NROWS * 4);
  float* b2   = (float*)alloc((size_t)NROWS * 4);
  float* posr = (float*)alloc((size_t)NROWS * 4);
  unsigned int* rowMin = (unsigned int*)alloc((size_t)NROWS * 4);
  int*   flag = (int*)alloc(256);
  float* tv   = (float*)alloc((size_t)NROWS * 32 * 4);
  int*   ti   = (int*)alloc((size_t)NROWS * 32 * 4);
  unsigned short* proj = (unsigned short*)alloc((size_t)2 * NROWS * NPROJ * 2);  // 2 MB
  float* pnorm = (float*)alloc((size_t)2 * NROWS * 4);                           // 128 KB
  const size_t remain = ws_size > off ? ws_size - off : 0;
  int chunk;
  if      (remain >= (size_t)NROWS * 8192 * 4) chunk = 8192;
  else if (remain >= (size_t)NROWS * 2048 * 4) chunk = 2048;
  else if (remain >= (size_t)NROWS * 512 * 4)  chunk = 512;
  else                                         chunk = 128;
  float* sqbuf = (float*)(ws + off);

  prep_kernel<<<NROWS, 256, 0, stream>>>(o1, o2, o1b, o2b, a2, b2, posr, rowMin, flag);
  proj_kernel<<<2 * NROWS / 128, 256, 0, stream>>>(o1b, proj, pnorm);
  gram64_kernel<<<dim3(64, 8), 256, 0, stream>>>(proj, pnorm, rowMin);
  flag_kernel<<<dim3(NROWS / 256), 256, 0, stream>>>(rowMin, flag);

  const int nch = NROWS / chunk;
  for (int c = 0; c < nch; ++c) {
    gemm_kernel<1><<<dim3(chunk / 128, 64), 256, 0, stream>>>(o1b, o2b, a2, b2, rowMin, flag,
                                                              sqbuf, c * chunk, chunk);
    const int first = (c == 0);
    if      (chunk == 8192) select_kernel<128><<<NROWS, 64, 0, stream>>>(sqbuf, flag, tv, ti, c * chunk, first);
    else if (chunk == 2048) select_kernel<32><<<NROWS, 64, 0, stream>>>(sqbuf, flag, tv, ti, c * chunk, first);
    else if (chunk == 512)  select_kernel<8><<<NROWS, 64, 0, stream>>>(sqbuf, flag, tv, ti, c * chunk, first);
    else                    select_kernel<2><<<NROWS, 64, 0, stream>>>(sqbuf, flag, tv, ti, c * chunk, first);
  }
  final_kernel<<<1, 256, 0, stream>>>(posr, tv, ti, rn, flag, out);
}